// Round 4
// baseline (1051.364 us; speedup 1.0000x reference)
//
#include <hip/hip_runtime.h>
#include <hip/hip_fp16.h>

// GCN2: h1 = relu(gcn(x,W1,b1)); h2 = relu(gcn(h1,W2,b2)); out = h2@Wlin+blin
// dinv[s] folded into fp16 h'; edges bucket-sorted by dst>>6 (counting sort
// with block-local runs so scattered writes coalesce in one XCD's L2);
// aggregation = per-bucket LDS fp32 accumulation with LDS float atomics.

constexpr int FDIM = 128;
constexpr int CDIM = 40;
constexpr int NPB  = 64;    // nodes per bucket
constexpr int MAXNB = 1024; // max buckets (n <= 65536)
constexpr int CH   = 4096;  // edges per partition block

static inline size_t AL512(size_t x) { return (x + 511) & ~size_t(511); }

// --- bucket histogram of dst>>6 ---
__global__ __launch_bounds__(256) void k_bhist(const int* __restrict__ dst,
        int* __restrict__ bcnt, int E, int nb) {
    __shared__ int h[MAXNB];
    for (int i = threadIdx.x; i < nb; i += 256) h[i] = 0;
    __syncthreads();
    for (int i = blockIdx.x * 256 + threadIdx.x; i < E; i += gridDim.x * 256)
        atomicAdd(&h[dst[i] >> 6], 1);
    __syncthreads();
    for (int i = threadIdx.x; i < nb; i += 256) {
        int c = h[i];
        if (c) atomicAdd(&bcnt[i], c);
    }
}

// --- single-block scan over nb bucket counts -> bbase, bcur ---
__global__ __launch_bounds__(1024) void k_bscan(const int* __restrict__ bcnt,
        int* __restrict__ bbase, int* __restrict__ bcur, int nb, int E) {
    __shared__ int tmp[1024];
    int t = threadIdx.x;
    int v = (t < nb) ? bcnt[t] : 0;
    tmp[t] = v;
    __syncthreads();
    for (int o = 1; o < 1024; o <<= 1) {
        int u = (t >= o) ? tmp[t - o] : 0;
        __syncthreads();
        tmp[t] += u;
        __syncthreads();
    }
    if (t < nb) { int b = tmp[t] - v; bbase[t] = b; bcur[t] = b; }
    if (t == 0) bbase[nb] = E;
}

// --- chunked counting sort: eb[] = edges grouped by bucket, packed
//     (src<<6)|(dst&63). Block-local contiguous runs -> coalescing writes. ---
__global__ __launch_bounds__(256) void k_partition(const int* __restrict__ src,
        const int* __restrict__ dst, int* __restrict__ bcur,
        unsigned* __restrict__ eb, int E, int nb) {
    __shared__ int hcnt[MAXNB];
    __shared__ int gb[MAXNB];
    int e0 = blockIdx.x * CH;
    int cnt = min(CH, E - e0);
    for (int i = threadIdx.x; i < nb; i += 256) hcnt[i] = 0;
    __syncthreads();
    for (int i = threadIdx.x; i < cnt; i += 256)
        atomicAdd(&hcnt[dst[e0 + i] >> 6], 1);
    __syncthreads();
    for (int i = threadIdx.x; i < nb; i += 256) {
        int c = hcnt[i];
        if (c) gb[i] = atomicAdd(&bcur[i], c);
        hcnt[i] = 0;  // reuse as local cursor
    }
    __syncthreads();
    for (int i = threadIdx.x; i < cnt; i += 256) {
        int d = dst[e0 + i], b = d >> 6;
        int p = atomicAdd(&hcnt[b], 1);
        eb[gb[b] + p] = ((unsigned)src[e0 + i] << 6) | (unsigned)(d & 63);
    }
}

// --- per-bucket node degree -> dinv (LDS histogram over bucketed edges) ---
__global__ __launch_bounds__(256) void k_degb(const unsigned* __restrict__ eb,
        const int* __restrict__ bbase, float* __restrict__ dinv, int n) {
    __shared__ int cnt[NPB];
    int b = blockIdx.x;
    if (threadIdx.x < NPB) cnt[threadIdx.x] = 0;
    __syncthreads();
    int beg = bbase[b], end = bbase[b + 1];
    for (int i = beg + threadIdx.x; i < end; i += 256)
        atomicAdd(&cnt[eb[i] & 63], 1);
    __syncthreads();
    int node = b * NPB + threadIdx.x;
    if (threadIdx.x < NPB && node < n)
        dinv[node] = rsqrtf((float)cnt[threadIdx.x] + 1.0f);  // +1 self loop
}

// Hp[r][c] = fp16( (X[r] @ W)[c] * dinv[r] )   (X: n x 128, W: 128 x 128)
__global__ __launch_bounds__(256) void k_gemm1(const float* __restrict__ X,
        const float* __restrict__ W, const float* __restrict__ dinv,
        __half* __restrict__ Hp, int n) {
    __shared__ float xs[16][128];
    int t = threadIdx.x;
    int r0 = blockIdx.x * 16;
    for (int i = t; i < 16 * 32; i += 256) {  // float4 staging
        int r = i >> 5, c4 = (i & 31) * 4;
        int gr = r0 + r;
        float4 v = make_float4(0.f, 0.f, 0.f, 0.f);
        if (gr < n) v = *reinterpret_cast<const float4*>(&X[(size_t)gr * 128 + c4]);
        *reinterpret_cast<float4*>(&xs[r][c4]) = v;
    }
    __syncthreads();
    int col = t & 127, half = t >> 7;
    float acc[8];
#pragma unroll
    for (int j = 0; j < 8; ++j) acc[j] = 0.f;
    for (int k = 0; k < 128; k += 4) {
        float w0 = W[k * 128 + col];
        float w1 = W[(k + 1) * 128 + col];
        float w2 = W[(k + 2) * 128 + col];
        float w3 = W[(k + 3) * 128 + col];
#pragma unroll
        for (int j = 0; j < 8; ++j) {
            const float4 xv = *reinterpret_cast<const float4*>(&xs[half + 2 * j][k]);
            acc[j] = fmaf(xv.w, w3, fmaf(xv.z, w2, fmaf(xv.y, w1, fmaf(xv.x, w0, acc[j]))));
        }
    }
#pragma unroll
    for (int j = 0; j < 8; ++j) {
        int gr = r0 + half + 2 * j;
        if (gr < n) Hp[(size_t)gr * 128 + col] = __float2half(acc[j] * dinv[gr]);
    }
}

// agg[d] = hp[d] + sum_{s->d} hp[s]  (D=128): one block per bucket,
// LDS fp32 accum, LDS float atomics, wave-wide 256B gathers.
__global__ __launch_bounds__(256) void k_bagg128(const unsigned* __restrict__ eb,
        const int* __restrict__ bbase, const __half* __restrict__ hp,
        float* __restrict__ agg, int n) {
    __shared__ float acc[NPB][FDIM];  // 32 KB
    int b = blockIdx.x, base = b * NPB;
    int tid = threadIdx.x;
    const __half2* hp2 = (const __half2*)hp;
    for (int i = tid; i < NPB * 64; i += 256) {  // init = self loop
        int r = i >> 6, c = i & 63;
        int node = base + r;
        float2 v = make_float2(0.f, 0.f);
        if (node < n) v = __half22float2(hp2[(size_t)node * 64 + c]);
        acc[r][2 * c] = v.x;
        acc[r][2 * c + 1] = v.y;
    }
    __syncthreads();
    int beg = bbase[b], end = bbase[b + 1];
    int lane = tid & 63, wv = tid >> 6;
    int e = beg + wv;
    for (; e + 4 < end; e += 8) {  // unroll 2 edges per wave
        unsigned p0 = eb[e], p1 = eb[e + 4];
        int s0 = p0 >> 6, d0 = p0 & 63;
        int s1 = p1 >> 6, d1 = p1 & 63;
        float2 v0 = __half22float2(hp2[(size_t)s0 * 64 + lane]);
        float2 v1 = __half22float2(hp2[(size_t)s1 * 64 + lane]);
        atomicAdd(&acc[d0][2 * lane], v0.x);
        atomicAdd(&acc[d0][2 * lane + 1], v0.y);
        atomicAdd(&acc[d1][2 * lane], v1.x);
        atomicAdd(&acc[d1][2 * lane + 1], v1.y);
    }
    for (; e < end; e += 4) {
        unsigned p0 = eb[e];
        int s0 = p0 >> 6, d0 = p0 & 63;
        float2 v0 = __half22float2(hp2[(size_t)s0 * 64 + lane]);
        atomicAdd(&acc[d0][2 * lane], v0.x);
        atomicAdd(&acc[d0][2 * lane + 1], v0.y);
    }
    __syncthreads();
    for (int i = tid; i < NPB * FDIM; i += 256) {
        int r = i >> 7, c = i & 127;
        int node = base + r;
        if (node < n) agg[(size_t)node * FDIM + c] = acc[r][c];
    }
}

// agg[d] = hp[d] + sum hp[s]  (D=40): same scheme, lanes 0..39 active.
__global__ __launch_bounds__(256) void k_bagg40(const unsigned* __restrict__ eb,
        const int* __restrict__ bbase, const __half* __restrict__ hp,
        float* __restrict__ agg, int n) {
    __shared__ float acc[NPB][CDIM];  // 10.25 KB
    int b = blockIdx.x, base = b * NPB;
    int tid = threadIdx.x;
    for (int i = tid; i < NPB * CDIM; i += 256) {
        int r = i / CDIM, c = i % CDIM;
        int node = base + r;
        acc[r][c] = (node < n) ? __half2float(hp[(size_t)node * CDIM + c]) : 0.f;
    }
    __syncthreads();
    int beg = bbase[b], end = bbase[b + 1];
    int lane = tid & 63, wv = tid >> 6;
    bool act = lane < CDIM;
    int e = beg + wv;
    for (; e + 4 < end; e += 8) {
        unsigned p0 = eb[e], p1 = eb[e + 4];
        int s0 = p0 >> 6, d0 = p0 & 63;
        int s1 = p1 >> 6, d1 = p1 & 63;
        if (act) {
            float v0 = __half2float(hp[(size_t)s0 * CDIM + lane]);
            float v1 = __half2float(hp[(size_t)s1 * CDIM + lane]);
            atomicAdd(&acc[d0][lane], v0);
            atomicAdd(&acc[d1][lane], v1);
        }
    }
    for (; e < end; e += 4) {
        unsigned p0 = eb[e];
        int s0 = p0 >> 6, d0 = p0 & 63;
        if (act) atomicAdd(&acc[d0][lane], __half2float(hp[(size_t)s0 * CDIM + lane]));
    }
    __syncthreads();
    for (int i = tid; i < NPB * CDIM; i += 256) {
        int r = i / CDIM, c = i % CDIM;
        int node = base + r;
        if (node < n) agg[(size_t)node * CDIM + c] = acc[r][c];
    }
}

// hp[r][c] = fp16( ( relu(dinv[r]*agg1[r] + b1) @ W2 )[c] * dinv[r] )
__global__ __launch_bounds__(320) void k_gemm2(const float* __restrict__ agg1,
        const float* __restrict__ b1, const float* __restrict__ W2,
        const float* __restrict__ dinv, __half* __restrict__ hp, int n) {
    __shared__ float xs[8][129];
    int t = threadIdx.x;
    int r0 = blockIdx.x * 8;
    for (int i = t; i < 8 * 128; i += 320) {
        int r = i >> 7, c = i & 127;
        int gr = r0 + r;
        xs[r][c] = (gr < n) ? fmaxf(fmaf(dinv[gr], agg1[(size_t)gr * 128 + c], b1[c]), 0.f)
                            : 0.f;
    }
    __syncthreads();
    int col = t % 40, r = t / 40;
    float acc = 0.f;
#pragma unroll
    for (int k = 0; k < 128; ++k) acc += xs[r][k] * W2[k * 40 + col];
    int gr = r0 + r;
    if (gr < n) hp[(size_t)gr * 40 + col] = __float2half(acc * dinv[gr]);
}

// h2 = relu(dinv[r]*agg2[r] + b2) -> h2_out ; lin_out = h2 @ Wlin + blin
__global__ __launch_bounds__(256) void k_final(const float* __restrict__ agg2,
        const float* __restrict__ b2, const float* __restrict__ Wlin,
        const float* __restrict__ blin, const float* __restrict__ dinv,
        float* __restrict__ h2_out, float* __restrict__ lin_out, int n) {
    __shared__ float wl[CDIM * CDIM];
    __shared__ float hs[32 * CDIM];
    int t = threadIdx.x;
    int r0 = blockIdx.x * 32;
    for (int i = t; i < CDIM * CDIM; i += 256) wl[i] = Wlin[i];
    for (int i = t; i < 32 * CDIM; i += 256) {
        int r = i / CDIM, c = i % CDIM;
        int gr = r0 + r;
        float v = 0.f;
        if (gr < n) {
            v = fmaxf(fmaf(dinv[gr], agg2[(size_t)gr * CDIM + c], b2[c]), 0.f);
            h2_out[(size_t)gr * CDIM + c] = v;
        }
        hs[i] = v;
    }
    __syncthreads();
    for (int i = t; i < 32 * CDIM; i += 256) {
        int r = i / CDIM, c = i % CDIM;
        int gr = r0 + r;
        if (gr >= n) continue;
        float acc = blin[c];
#pragma unroll
        for (int k = 0; k < CDIM; ++k) acc += hs[r * CDIM + k] * wl[k * CDIM + c];
        lin_out[(size_t)gr * CDIM + c] = acc;
    }
}

extern "C" void kernel_launch(void* const* d_in, const int* in_sizes, int n_in,
                              void* d_out, int out_size, void* d_ws, size_t ws_size,
                              hipStream_t stream) {
    const float* x    = (const float*)d_in[0];
    const int*   ei   = (const int*)d_in[1];
    const float* W1   = (const float*)d_in[2];
    const float* b1   = (const float*)d_in[3];
    const float* W2   = (const float*)d_in[4];
    const float* b2   = (const float*)d_in[5];
    const float* Wlin = (const float*)d_in[6];
    const float* blin = (const float*)d_in[7];
    float* out = (float*)d_out;

    const int n = in_sizes[0] / FDIM;
    const int E = in_sizes[1] / 2;
    const int* src = ei;
    const int* dst = ei + E;
    const int nb = (n + NPB - 1) / NPB;  // buckets

    char* ws = (char*)d_ws;
    size_t off = 0;
    int*      bcnt  = (int*)(ws + off);      off = AL512(off + (size_t)nb * 4);
    int*      bbase = (int*)(ws + off);      off = AL512(off + (size_t)(nb + 1) * 4);
    int*      bcur  = (int*)(ws + off);      off = AL512(off + (size_t)nb * 4);
    unsigned* eb    = (unsigned*)(ws + off); off = AL512(off + (size_t)E * 4);
    float*    dinv  = (float*)(ws + off);    off = AL512(off + (size_t)n * 4);
    __half*   hp1   = (__half*)(ws + off);   off = AL512(off + (size_t)n * FDIM * 2);
    float*    agg1  = (float*)(ws + off);    off = AL512(off + (size_t)n * FDIM * 4);
    __half*   hp2   = (__half*)(ws + off);   off = AL512(off + (size_t)n * CDIM * 2);
    float*    agg2  = (float*)(ws + off);    off = AL512(off + (size_t)n * CDIM * 4);
    (void)ws_size; (void)n_in; (void)out_size;

    float* h2_out  = out;
    float* lin_out = out + (size_t)n * CDIM;

    // bucket-sort edges by dst
    hipMemsetAsync(bcnt, 0, (size_t)nb * 4, stream);
    k_bhist<<<512, 256, 0, stream>>>(dst, bcnt, E, nb);
    k_bscan<<<1, 1024, 0, stream>>>(bcnt, bbase, bcur, nb, E);
    k_partition<<<(E + CH - 1) / CH, 256, 0, stream>>>(src, dst, bcur, eb, E, nb);
    k_degb<<<nb, 256, 0, stream>>>(eb, bbase, dinv, n);

    // conv1
    k_gemm1<<<(n + 15) / 16, 256, 0, stream>>>(x, W1, dinv, hp1, n);
    k_bagg128<<<nb, 256, 0, stream>>>(eb, bbase, hp1, agg1, n);

    // conv2
    k_gemm2<<<(n + 7) / 8, 320, 0, stream>>>(agg1, b1, W2, dinv, hp2, n);
    k_bagg40<<<nb, 256, 0, stream>>>(eb, bbase, hp2, agg2, n);

    // h2 + linear head
    k_final<<<(n + 31) / 32, 256, 0, stream>>>(agg2, b2, Wlin, blin, dinv, h2_out, lin_out, n);
}

// Round 5
// 219.998 us; speedup vs baseline: 4.7790x; 4.7790x over previous
//
#include <hip/hip_runtime.h>
#include <hip/hip_fp16.h>

// GCN2: h1 = relu(gcn(x,W1,b1)); h2 = relu(gcn(h1,W2,b2)); out = h2@Wlin+blin
// dinv[s] folded into fp16 h'. CSR built via bucket sort (dst>>6) with
// block-local contiguous write runs (coalescing-safe), then per-bucket
// counting sort to per-node lists. Aggregation: one wave per node, register
// accumulate (fp32) over fp16 gathers.

constexpr int FDIM = 128;
constexpr int CDIM = 40;
constexpr int NPB  = 64;    // nodes per bucket
constexpr int MAXNB = 1024; // max buckets (n <= 65536)
constexpr int CH   = 4096;  // edges per partition block

static inline size_t AL512(size_t x) { return (x + 511) & ~size_t(511); }

// --- bucket histogram of dst>>6 ---
__global__ __launch_bounds__(256) void k_bhist(const int* __restrict__ dst,
        int* __restrict__ bcnt, int E, int nb) {
    __shared__ int h[MAXNB];
    for (int i = threadIdx.x; i < nb; i += 256) h[i] = 0;
    __syncthreads();
    for (int i = blockIdx.x * 256 + threadIdx.x; i < E; i += gridDim.x * 256)
        atomicAdd(&h[dst[i] >> 6], 1);
    __syncthreads();
    for (int i = threadIdx.x; i < nb; i += 256) {
        int c = h[i];
        if (c) atomicAdd(&bcnt[i], c);
    }
}

// --- single-block scan over nb bucket counts -> bbase, bcur ---
__global__ __launch_bounds__(1024) void k_bscan(const int* __restrict__ bcnt,
        int* __restrict__ bbase, int* __restrict__ bcur, int nb, int E) {
    __shared__ int tmp[1024];
    int t = threadIdx.x;
    int v = (t < nb) ? bcnt[t] : 0;
    tmp[t] = v;
    __syncthreads();
    for (int o = 1; o < 1024; o <<= 1) {
        int u = (t >= o) ? tmp[t - o] : 0;
        __syncthreads();
        tmp[t] += u;
        __syncthreads();
    }
    if (t < nb) { int b = tmp[t] - v; bbase[t] = b; bcur[t] = b; }
    if (t == 0) bbase[nb] = E;
}

// --- chunked counting sort: eb[] = edges grouped by bucket, packed
//     (src<<6)|(dst&63). Block-local contiguous runs -> coalescing writes. ---
__global__ __launch_bounds__(256) void k_partition(const int* __restrict__ src,
        const int* __restrict__ dst, int* __restrict__ bcur,
        unsigned* __restrict__ eb, int E, int nb) {
    __shared__ int hcnt[MAXNB];
    __shared__ int gb[MAXNB];
    int e0 = blockIdx.x * CH;
    int cnt = min(CH, E - e0);
    for (int i = threadIdx.x; i < nb; i += 256) hcnt[i] = 0;
    __syncthreads();
    for (int i = threadIdx.x; i < cnt; i += 256)
        atomicAdd(&hcnt[dst[e0 + i] >> 6], 1);
    __syncthreads();
    for (int i = threadIdx.x; i < nb; i += 256) {
        int c = hcnt[i];
        if (c) gb[i] = atomicAdd(&bcur[i], c);
        hcnt[i] = 0;  // reuse as local cursor
    }
    __syncthreads();
    for (int i = threadIdx.x; i < cnt; i += 256) {
        int d = dst[e0 + i], b = d >> 6;
        int p = atomicAdd(&hcnt[b], 1);
        eb[gb[b] + p] = ((unsigned)src[e0 + i] << 6) | (unsigned)(d & 63);
    }
}

// --- per-bucket counting sort -> per-node CSR (offs, ss) + dinv.
//     All global writes land in the bucket's contiguous region. ---
__global__ __launch_bounds__(256) void k_bucket_csr(const unsigned* __restrict__ eb,
        const int* __restrict__ bbase, int* __restrict__ offs,
        float* __restrict__ dinv, int* __restrict__ ss, int n) {
    __shared__ int cnt[NPB];
    __shared__ int cur[NPB];
    int b = blockIdx.x;
    int beg = bbase[b], end = bbase[b + 1];
    if (threadIdx.x < NPB) cnt[threadIdx.x] = 0;
    __syncthreads();
    for (int i = beg + threadIdx.x; i < end; i += 256)
        atomicAdd(&cnt[eb[i] & 63], 1);
    __syncthreads();
    if (threadIdx.x < NPB) {  // wave 0: 64-lane inclusive shfl scan
        int v = cnt[threadIdx.x];
        int s = v;
#pragma unroll
        for (int o = 1; o < NPB; o <<= 1) {
            int u = __shfl_up(s, o, 64);
            if (threadIdx.x >= (unsigned)o) s += u;
        }
        int e0 = beg + s - v;  // exclusive prefix + bucket base
        cur[threadIdx.x] = e0;
        int node = b * NPB + threadIdx.x;
        if (node < n) {
            offs[node] = e0;
            dinv[node] = rsqrtf((float)v + 1.0f);  // +1 self loop
        }
    }
    __syncthreads();
    for (int i = beg + threadIdx.x; i < end; i += 256) {
        unsigned p = eb[i];
        int pos = atomicAdd(&cur[p & 63], 1);
        ss[pos] = (int)(p >> 6);
    }
}

// Hp[r][c] = fp16( (X[r] @ W)[c] * dinv[r] )   (X: n x 128, W: 128 x 128)
__global__ __launch_bounds__(256) void k_gemm1(const float* __restrict__ X,
        const float* __restrict__ W, const float* __restrict__ dinv,
        __half* __restrict__ Hp, int n) {
    __shared__ float xs[16][128];
    int t = threadIdx.x;
    int r0 = blockIdx.x * 16;
    for (int i = t; i < 16 * 32; i += 256) {  // float4 staging
        int r = i >> 5, c4 = (i & 31) * 4;
        int gr = r0 + r;
        float4 v = make_float4(0.f, 0.f, 0.f, 0.f);
        if (gr < n) v = *reinterpret_cast<const float4*>(&X[(size_t)gr * 128 + c4]);
        *reinterpret_cast<float4*>(&xs[r][c4]) = v;
    }
    __syncthreads();
    int col = t & 127, half = t >> 7;
    float acc[8];
#pragma unroll
    for (int j = 0; j < 8; ++j) acc[j] = 0.f;
    for (int k = 0; k < 128; k += 4) {
        float w0 = W[k * 128 + col];
        float w1 = W[(k + 1) * 128 + col];
        float w2 = W[(k + 2) * 128 + col];
        float w3 = W[(k + 3) * 128 + col];
#pragma unroll
        for (int j = 0; j < 8; ++j) {
            const float4 xv = *reinterpret_cast<const float4*>(&xs[half + 2 * j][k]);
            acc[j] = fmaf(xv.w, w3, fmaf(xv.z, w2, fmaf(xv.y, w1, fmaf(xv.x, w0, acc[j]))));
        }
    }
#pragma unroll
    for (int j = 0; j < 8; ++j) {
        int gr = r0 + half + 2 * j;
        if (gr < n) Hp[(size_t)gr * 128 + col] = __float2half(acc[j] * dinv[gr]);
    }
}

// agg[d] = h'[d] + sum_{s in CSR[d]} h'[s]  (D=128 fp16 rows, one wave/node,
// half2 per lane = 256B/row, fp32 accumulate, unroll 4)
__global__ __launch_bounds__(256) void k_agg128(const int* __restrict__ ss,
        const int* __restrict__ offs, const __half* __restrict__ hp,
        float* __restrict__ agg, int n, int E) {
    int w = (blockIdx.x * 256 + threadIdx.x) >> 6;
    int lane = threadIdx.x & 63;
    if (w >= n) return;
    int beg = offs[w];
    int end = (w == n - 1) ? E : offs[w + 1];
    const __half2* hpv = (const __half2*)hp;
    float2 acc = __half22float2(hpv[(size_t)w * 64 + lane]);  // self loop
    int j = beg;
    for (; j + 3 < end; j += 4) {
        int s0 = ss[j], s1 = ss[j + 1], s2 = ss[j + 2], s3 = ss[j + 3];
        float2 a = __half22float2(hpv[(size_t)s0 * 64 + lane]);
        float2 b = __half22float2(hpv[(size_t)s1 * 64 + lane]);
        float2 c = __half22float2(hpv[(size_t)s2 * 64 + lane]);
        float2 d = __half22float2(hpv[(size_t)s3 * 64 + lane]);
        acc.x += (a.x + b.x) + (c.x + d.x);
        acc.y += (a.y + b.y) + (c.y + d.y);
    }
    for (; j < end; ++j) {
        int s = ss[j];
        float2 a = __half22float2(hpv[(size_t)s * 64 + lane]);
        acc.x += a.x;
        acc.y += a.y;
    }
    ((float2*)agg)[(size_t)w * 64 + lane] = acc;
}

// agg[d] = h'[d] + sum h'[s]  (D=40 fp16 rows, one wave/node, lanes 0..39)
__global__ __launch_bounds__(256) void k_agg40(const int* __restrict__ ss,
        const int* __restrict__ offs, const __half* __restrict__ hp,
        float* __restrict__ agg, int n, int E) {
    int w = (blockIdx.x * 256 + threadIdx.x) >> 6;
    int lane = threadIdx.x & 63;
    if (w >= n) return;
    int beg = offs[w];
    int end = (w == n - 1) ? E : offs[w + 1];
    bool act = lane < CDIM;
    float acc = act ? __half2float(hp[(size_t)w * CDIM + lane]) : 0.f;
    int j = beg;
    for (; j + 3 < end; j += 4) {
        int s0 = ss[j], s1 = ss[j + 1], s2 = ss[j + 2], s3 = ss[j + 3];
        if (act) {
            float a = __half2float(hp[(size_t)s0 * CDIM + lane]);
            float b = __half2float(hp[(size_t)s1 * CDIM + lane]);
            float c = __half2float(hp[(size_t)s2 * CDIM + lane]);
            float d = __half2float(hp[(size_t)s3 * CDIM + lane]);
            acc += (a + b) + (c + d);
        }
    }
    for (; j < end; ++j) {
        int s = ss[j];
        if (act) acc += __half2float(hp[(size_t)s * CDIM + lane]);
    }
    if (act) agg[(size_t)w * CDIM + lane] = acc;
}

// hp[r][c] = fp16( ( relu(dinv[r]*agg1[r] + b1) @ W2 )[c] * dinv[r] )
__global__ __launch_bounds__(320) void k_gemm2(const float* __restrict__ agg1,
        const float* __restrict__ b1, const float* __restrict__ W2,
        const float* __restrict__ dinv, __half* __restrict__ hp, int n) {
    __shared__ float xs[8][129];
    int t = threadIdx.x;
    int r0 = blockIdx.x * 8;
    for (int i = t; i < 8 * 128; i += 320) {
        int r = i >> 7, c = i & 127;
        int gr = r0 + r;
        xs[r][c] = (gr < n) ? fmaxf(fmaf(dinv[gr], agg1[(size_t)gr * 128 + c], b1[c]), 0.f)
                            : 0.f;
    }
    __syncthreads();
    int col = t % 40, r = t / 40;
    float acc = 0.f;
#pragma unroll
    for (int k = 0; k < 128; ++k) acc += xs[r][k] * W2[k * 40 + col];
    int gr = r0 + r;
    if (gr < n) hp[(size_t)gr * 40 + col] = __float2half(acc * dinv[gr]);
}

// h2 = relu(dinv[r]*agg2[r] + b2) -> h2_out ; lin_out = h2 @ Wlin + blin
__global__ __launch_bounds__(256) void k_final(const float* __restrict__ agg2,
        const float* __restrict__ b2, const float* __restrict__ Wlin,
        const float* __restrict__ blin, const float* __restrict__ dinv,
        float* __restrict__ h2_out, float* __restrict__ lin_out, int n) {
    __shared__ float wl[CDIM * CDIM];
    __shared__ float hs[32 * CDIM];
    int t = threadIdx.x;
    int r0 = blockIdx.x * 32;
    for (int i = t; i < CDIM * CDIM; i += 256) wl[i] = Wlin[i];
    for (int i = t; i < 32 * CDIM; i += 256) {
        int r = i / CDIM, c = i % CDIM;
        int gr = r0 + r;
        float v = 0.f;
        if (gr < n) {
            v = fmaxf(fmaf(dinv[gr], agg2[(size_t)gr * CDIM + c], b2[c]), 0.f);
            h2_out[(size_t)gr * CDIM + c] = v;
        }
        hs[i] = v;
    }
    __syncthreads();
    for (int i = t; i < 32 * CDIM; i += 256) {
        int r = i / CDIM, c = i % CDIM;
        int gr = r0 + r;
        if (gr >= n) continue;
        float acc = blin[c];
#pragma unroll
        for (int k = 0; k < CDIM; ++k) acc += hs[r * CDIM + k] * wl[k * CDIM + c];
        lin_out[(size_t)gr * CDIM + c] = acc;
    }
}

extern "C" void kernel_launch(void* const* d_in, const int* in_sizes, int n_in,
                              void* d_out, int out_size, void* d_ws, size_t ws_size,
                              hipStream_t stream) {
    const float* x    = (const float*)d_in[0];
    const int*   ei   = (const int*)d_in[1];
    const float* W1   = (const float*)d_in[2];
    const float* b1   = (const float*)d_in[3];
    const float* W2   = (const float*)d_in[4];
    const float* b2   = (const float*)d_in[5];
    const float* Wlin = (const float*)d_in[6];
    const float* blin = (const float*)d_in[7];
    float* out = (float*)d_out;

    const int n = in_sizes[0] / FDIM;
    const int E = in_sizes[1] / 2;
    const int* src = ei;
    const int* dst = ei + E;
    const int nb = (n + NPB - 1) / NPB;

    char* ws = (char*)d_ws;
    size_t off = 0;
    int*      bcnt  = (int*)(ws + off);      off = AL512(off + (size_t)nb * 4);
    int*      bbase = (int*)(ws + off);      off = AL512(off + (size_t)(nb + 1) * 4);
    int*      bcur  = (int*)(ws + off);      off = AL512(off + (size_t)nb * 4);
    unsigned* eb    = (unsigned*)(ws + off); off = AL512(off + (size_t)E * 4);
    int*      offs  = (int*)(ws + off);      off = AL512(off + (size_t)n * 4);
    int*      ss    = (int*)(ws + off);      off = AL512(off + (size_t)E * 4);
    float*    dinv  = (float*)(ws + off);    off = AL512(off + (size_t)n * 4);
    __half*   hp1   = (__half*)(ws + off);   off = AL512(off + (size_t)n * FDIM * 2);
    float*    agg1  = (float*)(ws + off);    off = AL512(off + (size_t)n * FDIM * 4);
    __half*   hp2   = (__half*)(ws + off);   off = AL512(off + (size_t)n * CDIM * 2);
    float*    agg2  = (float*)(ws + off);    off = AL512(off + (size_t)n * CDIM * 4);
    (void)ws_size; (void)n_in; (void)out_size;

    float* h2_out  = out;
    float* lin_out = out + (size_t)n * CDIM;

    // CSR build: bucket sort by dst>>6, then per-bucket counting sort
    hipMemsetAsync(bcnt, 0, (size_t)nb * 4, stream);
    k_bhist<<<256, 256, 0, stream>>>(dst, bcnt, E, nb);
    k_bscan<<<1, 1024, 0, stream>>>(bcnt, bbase, bcur, nb, E);
    k_partition<<<(E + CH - 1) / CH, 256, 0, stream>>>(src, dst, bcur, eb, E, nb);
    k_bucket_csr<<<nb, 256, 0, stream>>>(eb, bbase, offs, dinv, ss, n);

    // conv1
    k_gemm1<<<(n + 15) / 16, 256, 0, stream>>>(x, W1, dinv, hp1, n);
    k_agg128<<<(n * 64 + 255) / 256, 256, 0, stream>>>(ss, offs, hp1, agg1, n, E);

    // conv2
    k_gemm2<<<(n + 7) / 8, 320, 0, stream>>>(agg1, b1, W2, dinv, hp2, n);
    k_agg40<<<(n * 64 + 255) / 256, 256, 0, stream>>>(ss, offs, hp2, agg2, n, E);

    // h2 + linear head
    k_final<<<(n + 31) / 32, 256, 0, stream>>>(agg2, b2, Wlin, blin, dinv, h2_out, lin_out, n);
}

// Round 6
// 171.646 us; speedup vs baseline: 6.1252x; 1.2817x over previous
//
#include <hip/hip_runtime.h>

// GCN2: h1 = relu(gcn(x,W1,b1)); h2 = relu(gcn(h1,W2,b2)); out = h2@Wlin+blin
// dinv[s] folded into fp16 h'. CSR via bucket sort (dst>>6) with block-local
// contiguous write runs. Aggregation: one wave per node, fp32 register accum
// over fp16 gathers, bias+relu+dinv fused into the epilogue. Dense GEMMs use
// v_mfma_f32_16x16x32_f16 (fp16 in, fp32 accum). Fragment k-order is safe by
// the bijection argument (A,B loaded with the same (group,slot)->k map);
// C/D layout col=lane&15,row=(lane>>4)*4+reg is HW-verified.

constexpr int FDIM = 128;
constexpr int CDIM = 40;
constexpr int NPB  = 64;    // nodes per bucket
constexpr int MAXNB = 1024; // max buckets
constexpr int CH   = 4096;  // edges per partition block

typedef _Float16 h8  __attribute__((ext_vector_type(8)));
typedef _Float16 h4  __attribute__((ext_vector_type(4)));
typedef _Float16 h2v __attribute__((ext_vector_type(2)));
typedef float    f4  __attribute__((ext_vector_type(4)));

static inline size_t AL512(size_t x) { return (x + 511) & ~size_t(511); }

// --- bucket histogram of dst>>6 ---
__global__ __launch_bounds__(256) void k_bhist(const int* __restrict__ dst,
        int* __restrict__ bcnt, int E, int nb) {
    __shared__ int h[MAXNB];
    for (int i = threadIdx.x; i < nb; i += 256) h[i] = 0;
    __syncthreads();
    for (int i = blockIdx.x * 256 + threadIdx.x; i < E; i += gridDim.x * 256)
        atomicAdd(&h[dst[i] >> 6], 1);
    __syncthreads();
    for (int i = threadIdx.x; i < nb; i += 256) {
        int c = h[i];
        if (c) atomicAdd(&bcnt[i], c);
    }
}

// --- single-block scan over nb bucket counts -> bbase, bcur ---
__global__ __launch_bounds__(1024) void k_bscan(const int* __restrict__ bcnt,
        int* __restrict__ bbase, int* __restrict__ bcur, int nb, int E) {
    __shared__ int tmp[1024];
    int t = threadIdx.x;
    int v = (t < nb) ? bcnt[t] : 0;
    tmp[t] = v;
    __syncthreads();
    for (int o = 1; o < 1024; o <<= 1) {
        int u = (t >= o) ? tmp[t - o] : 0;
        __syncthreads();
        tmp[t] += u;
        __syncthreads();
    }
    if (t < nb) { int b = tmp[t] - v; bbase[t] = b; bcur[t] = b; }
    if (t == 0) bbase[nb] = E;
}

// --- chunked counting sort into bucket runs, packed (src<<6)|(dst&63) ---
__global__ __launch_bounds__(256) void k_partition(const int* __restrict__ src,
        const int* __restrict__ dst, int* __restrict__ bcur,
        unsigned* __restrict__ eb, int E, int nb) {
    __shared__ int hcnt[MAXNB];
    __shared__ int gb[MAXNB];
    int e0 = blockIdx.x * CH;
    int cnt = min(CH, E - e0);
    for (int i = threadIdx.x; i < nb; i += 256) hcnt[i] = 0;
    __syncthreads();
    for (int i = threadIdx.x; i < cnt; i += 256)
        atomicAdd(&hcnt[dst[e0 + i] >> 6], 1);
    __syncthreads();
    for (int i = threadIdx.x; i < nb; i += 256) {
        int c = hcnt[i];
        if (c) gb[i] = atomicAdd(&bcur[i], c);
        hcnt[i] = 0;  // reuse as local cursor
    }
    __syncthreads();
    for (int i = threadIdx.x; i < cnt; i += 256) {
        int d = dst[e0 + i], b = d >> 6;
        int p = atomicAdd(&hcnt[b], 1);
        eb[gb[b] + p] = ((unsigned)src[e0 + i] << 6) | (unsigned)(d & 63);
    }
}

// --- per-bucket counting sort -> per-node CSR (offs, ss) + dinv ---
__global__ __launch_bounds__(256) void k_bucket_csr(const unsigned* __restrict__ eb,
        const int* __restrict__ bbase, int* __restrict__ offs,
        float* __restrict__ dinv, int* __restrict__ ss, int n) {
    __shared__ int cnt[NPB];
    __shared__ int cur[NPB];
    int b = blockIdx.x;
    int beg = bbase[b], end = bbase[b + 1];
    if (threadIdx.x < NPB) cnt[threadIdx.x] = 0;
    __syncthreads();
    for (int i = beg + threadIdx.x; i < end; i += 256)
        atomicAdd(&cnt[eb[i] & 63], 1);
    __syncthreads();
    if (threadIdx.x < NPB) {  // wave 0: 64-lane inclusive shfl scan
        int v = cnt[threadIdx.x];
        int s = v;
#pragma unroll
        for (int o = 1; o < NPB; o <<= 1) {
            int u = __shfl_up(s, o, 64);
            if (threadIdx.x >= (unsigned)o) s += u;
        }
        int e0 = beg + s - v;
        cur[threadIdx.x] = e0;
        int node = b * NPB + threadIdx.x;
        if (node < n) {
            offs[node] = e0;
            dinv[node] = rsqrtf((float)v + 1.0f);  // +1 self loop
        }
    }
    __syncthreads();
    for (int i = beg + threadIdx.x; i < end; i += 256) {
        unsigned p = eb[i];
        int pos = atomicAdd(&cur[p & 63], 1);
        ss[pos] = (int)(p >> 6);
    }
}

// --- weight prep: W1t[c][k]=fp16(W1[k][c]); W2t[c][k]=fp16(W2[k][c]), 48 cols ---
__global__ __launch_bounds__(256) void k_prep(const float* __restrict__ W1,
        const float* __restrict__ W2, _Float16* __restrict__ W1t,
        _Float16* __restrict__ W2t) {
    int i = blockIdx.x * 256 + threadIdx.x;
    if (i < 128 * 128) {
        int c = i >> 7, k = i & 127;
        W1t[c * 128 + k] = (_Float16)W1[k * 128 + c];
    }
    int j = i - 128 * 128;
    if (j >= 0 && j < 48 * 128) {
        int c = j >> 7, k = j & 127;
        W2t[c * 128 + k] = (c < CDIM) ? (_Float16)W2[k * CDIM + c] : (_Float16)0.f;
    }
}

// Hp[r][c] = fp16( (X[r] @ W1)[c] * dinv[r] )  -- MFMA 16x16x32 f16
__global__ __launch_bounds__(256) void k_gemm1(const float* __restrict__ X,
        const _Float16* __restrict__ W1t, const float* __restrict__ dinv,
        _Float16* __restrict__ Hp, int n) {
    __shared__ _Float16 xh[64][136];   // +8 pad: 2-way LDS conflict (free)
    __shared__ _Float16 wt[128][136];
    int t = threadIdx.x;
    int r0 = blockIdx.x * 64;
    for (int i = t; i < 64 * 32; i += 256) {
        int r = i >> 5, c4 = (i & 31) * 4;
        int gr = r0 + r;
        float4 v = make_float4(0.f, 0.f, 0.f, 0.f);
        if (gr < n) v = *(const float4*)&X[(size_t)gr * 128 + c4];
        h4 hv; hv[0] = (_Float16)v.x; hv[1] = (_Float16)v.y;
               hv[2] = (_Float16)v.z; hv[3] = (_Float16)v.w;
        *(h4*)&xh[r][c4] = hv;
    }
    for (int i = t; i < 128 * 16; i += 256) {
        int r = i >> 4, c8 = (i & 15) * 8;
        *(uint4*)&wt[r][c8] = *(const uint4*)&W1t[r * 128 + c8];
    }
    __syncthreads();
    int wid = t >> 6, lane = t & 63;
    int fr = lane & 15, fg = lane >> 4;
    f4 acc[8];
#pragma unroll
    for (int ct = 0; ct < 8; ++ct) acc[ct] = (f4){0.f, 0.f, 0.f, 0.f};
#pragma unroll
    for (int ks = 0; ks < 4; ++ks) {
        h8 a = *(const h8*)&xh[wid * 16 + fr][ks * 32 + fg * 8];
#pragma unroll
        for (int ct = 0; ct < 8; ++ct) {
            h8 b = *(const h8*)&wt[ct * 16 + fr][ks * 32 + fg * 8];
            acc[ct] = __builtin_amdgcn_mfma_f32_16x16x32_f16(a, b, acc[ct], 0, 0, 0);
        }
    }
    int rbase = r0 + wid * 16 + fg * 4;  // C/D: row=(lane>>4)*4+reg, col=lane&15
    float dv[4];
#pragma unroll
    for (int rg = 0; rg < 4; ++rg) dv[rg] = (rbase + rg < n) ? dinv[rbase + rg] : 0.f;
#pragma unroll
    for (int ct = 0; ct < 8; ++ct)
#pragma unroll
        for (int rg = 0; rg < 4; ++rg) {
            int gr = rbase + rg;
            if (gr < n) Hp[(size_t)gr * 128 + ct * 16 + fr] = (_Float16)(acc[ct][rg] * dv[rg]);
        }
}

// h1[d] = fp16(relu(dinv[d]*(hp[d]+sum hp[s]) + b1))  (fp32 accum, fused epi)
__global__ __launch_bounds__(256) void k_agg128(const int* __restrict__ ss,
        const int* __restrict__ offs, const _Float16* __restrict__ hp,
        const float* __restrict__ b1, const float* __restrict__ dinv,
        _Float16* __restrict__ h1, int n, int E) {
    int w = (blockIdx.x * 256 + threadIdx.x) >> 6;
    int lane = threadIdx.x & 63;
    if (w >= n) return;
    int beg = offs[w];
    int end = (w == n - 1) ? E : offs[w + 1];
    const h2v* hpv = (const h2v*)hp;
    h2v sv = hpv[(size_t)w * 64 + lane];  // self loop
    float ax = (float)sv[0], ay = (float)sv[1];
    int j = beg;
    for (; j + 3 < end; j += 4) {
        int s0 = ss[j], s1 = ss[j + 1], s2 = ss[j + 2], s3 = ss[j + 3];
        h2v a = hpv[(size_t)s0 * 64 + lane];
        h2v b = hpv[(size_t)s1 * 64 + lane];
        h2v c = hpv[(size_t)s2 * 64 + lane];
        h2v d = hpv[(size_t)s3 * 64 + lane];
        ax += ((float)a[0] + (float)b[0]) + ((float)c[0] + (float)d[0]);
        ay += ((float)a[1] + (float)b[1]) + ((float)c[1] + (float)d[1]);
    }
    for (; j < end; ++j) {
        int s = ss[j];
        h2v a = hpv[(size_t)s * 64 + lane];
        ax += (float)a[0];
        ay += (float)a[1];
    }
    float dvv = dinv[w];
    float2 bb = *(const float2*)&b1[2 * lane];
    h2v o;
    o[0] = (_Float16)fmaxf(fmaf(dvv, ax, bb.x), 0.f);
    o[1] = (_Float16)fmaxf(fmaf(dvv, ay, bb.y), 0.f);
    *(h2v*)&h1[(size_t)w * 128 + 2 * lane] = o;
}

// Hp2[r][c] = fp16( (h1[r] @ W2)[c] * dinv[r] )  -- MFMA, 48-col padded
__global__ __launch_bounds__(256) void k_gemm2(const _Float16* __restrict__ H1,
        const _Float16* __restrict__ W2t, const float* __restrict__ dinv,
        _Float16* __restrict__ Hp2, int n) {
    __shared__ _Float16 xh[64][136];
    __shared__ _Float16 wt[48][136];
    int t = threadIdx.x;
    int r0 = blockIdx.x * 64;
    for (int i = t; i < 64 * 16; i += 256) {
        int r = i >> 4, c8 = (i & 15) * 8;
        int gr = r0 + r;
        uint4 v = make_uint4(0u, 0u, 0u, 0u);
        if (gr < n) v = *(const uint4*)&H1[(size_t)gr * 128 + c8];
        *(uint4*)&xh[r][c8] = v;
    }
    for (int i = t; i < 48 * 16; i += 256) {
        int r = i >> 4, c8 = (i & 15) * 8;
        *(uint4*)&wt[r][c8] = *(const uint4*)&W2t[r * 128 + c8];
    }
    __syncthreads();
    int wid = t >> 6, lane = t & 63;
    int fr = lane & 15, fg = lane >> 4;
    f4 acc[3];
#pragma unroll
    for (int ct = 0; ct < 3; ++ct) acc[ct] = (f4){0.f, 0.f, 0.f, 0.f};
#pragma unroll
    for (int ks = 0; ks < 4; ++ks) {
        h8 a = *(const h8*)&xh[wid * 16 + fr][ks * 32 + fg * 8];
#pragma unroll
        for (int ct = 0; ct < 3; ++ct) {
            h8 b = *(const h8*)&wt[ct * 16 + fr][ks * 32 + fg * 8];
            acc[ct] = __builtin_amdgcn_mfma_f32_16x16x32_f16(a, b, acc[ct], 0, 0, 0);
        }
    }
    int rbase = r0 + wid * 16 + fg * 4;
    float dv[4];
#pragma unroll
    for (int rg = 0; rg < 4; ++rg) dv[rg] = (rbase + rg < n) ? dinv[rbase + rg] : 0.f;
#pragma unroll
    for (int ct = 0; ct < 3; ++ct)
#pragma unroll
        for (int rg = 0; rg < 4; ++rg) {
            int gr = rbase + rg, gc = ct * 16 + fr;
            if (gr < n && gc < CDIM)
                Hp2[(size_t)gr * CDIM + gc] = (_Float16)(acc[ct][rg] * dv[rg]);
        }
}

// h2[d] = relu(dinv[d]*(hp2[d]+sum hp2[s]) + b2) -> written to d_out directly
__global__ __launch_bounds__(256) void k_agg40(const int* __restrict__ ss,
        const int* __restrict__ offs, const _Float16* __restrict__ hp,
        const float* __restrict__ b2, const float* __restrict__ dinv,
        float* __restrict__ h2out, int n, int E) {
    int w = (blockIdx.x * 256 + threadIdx.x) >> 6;
    int lane = threadIdx.x & 63;
    if (w >= n) return;
    int beg = offs[w];
    int end = (w == n - 1) ? E : offs[w + 1];
    bool act = lane < CDIM;
    float acc = act ? (float)hp[(size_t)w * CDIM + lane] : 0.f;
    int j = beg;
    for (; j + 3 < end; j += 4) {
        int s0 = ss[j], s1 = ss[j + 1], s2 = ss[j + 2], s3 = ss[j + 3];
        if (act) {
            float a = (float)hp[(size_t)s0 * CDIM + lane];
            float b = (float)hp[(size_t)s1 * CDIM + lane];
            float c = (float)hp[(size_t)s2 * CDIM + lane];
            float d = (float)hp[(size_t)s3 * CDIM + lane];
            acc += (a + b) + (c + d);
        }
    }
    for (; j < end; ++j) {
        int s = ss[j];
        if (act) acc += (float)hp[(size_t)s * CDIM + lane];
    }
    if (act) h2out[(size_t)w * CDIM + lane] = fmaxf(fmaf(dinv[w], acc, b2[lane]), 0.f);
}

// lin_out = h2 @ Wlin + blin  (h2 read back from d_out)
__global__ __launch_bounds__(256) void k_final(const float* __restrict__ h2,
        const float* __restrict__ Wlin, const float* __restrict__ blin,
        float* __restrict__ lin_out, int n) {
    __shared__ float wl[CDIM * CDIM];
    __shared__ float hs[32 * CDIM];
    int t = threadIdx.x;
    int r0 = blockIdx.x * 32;
    for (int i = t; i < CDIM * CDIM; i += 256) wl[i] = Wlin[i];
    int lim = n * CDIM - r0 * CDIM;
    for (int i = t; i < 32 * CDIM; i += 256)
        hs[i] = (i < lim) ? h2[(size_t)r0 * CDIM + i] : 0.f;
    __syncthreads();
    for (int i = t; i < 32 * CDIM; i += 256) {
        int r = i / CDIM, c = i % CDIM;
        int gr = r0 + r;
        if (gr >= n) continue;
        float acc = blin[c];
#pragma unroll
        for (int k = 0; k < CDIM; ++k) acc = fmaf(hs[r * CDIM + k], wl[k * CDIM + c], acc);
        lin_out[(size_t)gr * CDIM + c] = acc;
    }
}

extern "C" void kernel_launch(void* const* d_in, const int* in_sizes, int n_in,
                              void* d_out, int out_size, void* d_ws, size_t ws_size,
                              hipStream_t stream) {
    const float* x    = (const float*)d_in[0];
    const int*   ei   = (const int*)d_in[1];
    const float* W1   = (const float*)d_in[2];
    const float* b1   = (const float*)d_in[3];
    const float* W2   = (const float*)d_in[4];
    const float* b2   = (const float*)d_in[5];
    const float* Wlin = (const float*)d_in[6];
    const float* blin = (const float*)d_in[7];
    float* out = (float*)d_out;

    const int n = in_sizes[0] / FDIM;
    const int E = in_sizes[1] / 2;
    const int* src = ei;
    const int* dst = ei + E;
    const int nb = (n + NPB - 1) / NPB;

    char* ws = (char*)d_ws;
    size_t off = 0;
    int*       bcnt  = (int*)(ws + off);       off = AL512(off + (size_t)nb * 4);
    int*       bbase = (int*)(ws + off);       off = AL512(off + (size_t)(nb + 1) * 4);
    int*       bcur  = (int*)(ws + off);       off = AL512(off + (size_t)nb * 4);
    unsigned*  eb    = (unsigned*)(ws + off);  off = AL512(off + (size_t)E * 4);
    int*       offs  = (int*)(ws + off);       off = AL512(off + (size_t)n * 4);
    int*       ss    = (int*)(ws + off);       off = AL512(off + (size_t)E * 4);
    float*     dinv  = (float*)(ws + off);     off = AL512(off + (size_t)n * 4);
    _Float16*  W1t   = (_Float16*)(ws + off);  off = AL512(off + (size_t)128 * 128 * 2);
    _Float16*  W2t   = (_Float16*)(ws + off);  off = AL512(off + (size_t)48 * 128 * 2);
    _Float16*  hp1   = (_Float16*)(ws + off);  off = AL512(off + (size_t)n * FDIM * 2);
    _Float16*  h1h   = (_Float16*)(ws + off);  off = AL512(off + (size_t)n * FDIM * 2);
    _Float16*  hp2   = (_Float16*)(ws + off);  off = AL512(off + (size_t)n * CDIM * 2);
    (void)ws_size; (void)n_in; (void)out_size;

    float* h2_out  = out;
    float* lin_out = out + (size_t)n * CDIM;

    // weight prep (independent) + CSR build
    k_prep<<<(128 * 128 + 48 * 128 + 255) / 256, 256, 0, stream>>>(W1, W2, W1t, W2t);
    hipMemsetAsync(bcnt, 0, (size_t)nb * 4, stream);
    k_bhist<<<256, 256, 0, stream>>>(dst, bcnt, E, nb);
    k_bscan<<<1, 1024, 0, stream>>>(bcnt, bbase, bcur, nb, E);
    k_partition<<<(E + CH - 1) / CH, 256, 0, stream>>>(src, dst, bcur, eb, E, nb);
    k_bucket_csr<<<nb, 256, 0, stream>>>(eb, bbase, offs, dinv, ss, n);

    // conv1
    k_gemm1<<<(n + 63) / 64, 256, 0, stream>>>(x, W1t, dinv, hp1, n);
    k_agg128<<<(n * 64 + 255) / 256, 256, 0, stream>>>(ss, offs, hp1, b1, dinv, h1h, n, E);

    // conv2
    k_gemm2<<<(n + 63) / 64, 256, 0, stream>>>(h1h, W2t, dinv, hp2, n);
    k_agg40<<<(n * 64 + 255) / 256, 256, 0, stream>>>(ss, offs, hp2, b2, dinv, h2_out, n, E);

    // linear head
    k_final<<<(n + 31) / 32, 256, 0, stream>>>(h2_out, Wlin, blin, lin_out, n);
}

// Round 7
// 150.514 us; speedup vs baseline: 6.9852x; 1.1404x over previous
//
#include <hip/hip_runtime.h>

// GCN2: h1 = relu(gcn(x,W1,b1)); h2 = relu(gcn(h1,W2,b2)); out = h2@Wlin+blin
// dinv[s] folded into fp16 h'. CSR via bucket sort (dst>>6) with block-local
// contiguous write runs. Dense GEMMs on v_mfma_f32_16x16x32_f16 (fp32 accum).
// Aggregation: one wave per node, 16B/lane gathers fetch 4 (D=128) or 8
// (D=64-padded) neighbor rows per load instruction; group partials folded by
// __shfl_xor once per node. Epilogue (dinv+bias+relu) fused into aggregation.

constexpr int FDIM = 128;
constexpr int CDIM = 40;
constexpr int NPB  = 64;    // nodes per bucket
constexpr int MAXNB = 1024; // max buckets
constexpr int CH   = 4096;  // edges per partition block

typedef _Float16 h8  __attribute__((ext_vector_type(8)));
typedef _Float16 h4  __attribute__((ext_vector_type(4)));
typedef float    f4  __attribute__((ext_vector_type(4)));

static inline size_t AL512(size_t x) { return (x + 511) & ~size_t(511); }

// --- bucket histogram of dst>>6 ---
__global__ __launch_bounds__(256) void k_bhist(const int* __restrict__ dst,
        int* __restrict__ bcnt, int E, int nb) {
    __shared__ int h[MAXNB];
    for (int i = threadIdx.x; i < nb; i += 256) h[i] = 0;
    __syncthreads();
    for (int i = blockIdx.x * 256 + threadIdx.x; i < E; i += gridDim.x * 256)
        atomicAdd(&h[dst[i] >> 6], 1);
    __syncthreads();
    for (int i = threadIdx.x; i < nb; i += 256) {
        int c = h[i];
        if (c) atomicAdd(&bcnt[i], c);
    }
}

// --- single-block scan over nb bucket counts -> bbase, bcur ---
__global__ __launch_bounds__(1024) void k_bscan(const int* __restrict__ bcnt,
        int* __restrict__ bbase, int* __restrict__ bcur, int nb, int E) {
    __shared__ int tmp[1024];
    int t = threadIdx.x;
    int v = (t < nb) ? bcnt[t] : 0;
    tmp[t] = v;
    __syncthreads();
    for (int o = 1; o < 1024; o <<= 1) {
        int u = (t >= o) ? tmp[t - o] : 0;
        __syncthreads();
        tmp[t] += u;
        __syncthreads();
    }
    if (t < nb) { int b = tmp[t] - v; bbase[t] = b; bcur[t] = b; }
    if (t == 0) bbase[nb] = E;
}

// --- chunked counting sort into bucket runs, packed (src<<6)|(dst&63) ---
__global__ __launch_bounds__(256) void k_partition(const int* __restrict__ src,
        const int* __restrict__ dst, int* __restrict__ bcur,
        unsigned* __restrict__ eb, int E, int nb) {
    __shared__ int hcnt[MAXNB];
    __shared__ int gb[MAXNB];
    int e0 = blockIdx.x * CH;
    int cnt = min(CH, E - e0);
    for (int i = threadIdx.x; i < nb; i += 256) hcnt[i] = 0;
    __syncthreads();
    for (int i = threadIdx.x; i < cnt; i += 256)
        atomicAdd(&hcnt[dst[e0 + i] >> 6], 1);
    __syncthreads();
    for (int i = threadIdx.x; i < nb; i += 256) {
        int c = hcnt[i];
        if (c) gb[i] = atomicAdd(&bcur[i], c);
        hcnt[i] = 0;  // reuse as local cursor
    }
    __syncthreads();
    for (int i = threadIdx.x; i < cnt; i += 256) {
        int d = dst[e0 + i], b = d >> 6;
        int p = atomicAdd(&hcnt[b], 1);
        eb[gb[b] + p] = ((unsigned)src[e0 + i] << 6) | (unsigned)(d & 63);
    }
}

// --- per-bucket counting sort -> per-node CSR (offs, ss) + dinv ---
__global__ __launch_bounds__(256) void k_bucket_csr(const unsigned* __restrict__ eb,
        const int* __restrict__ bbase, int* __restrict__ offs,
        float* __restrict__ dinv, int* __restrict__ ss, int n) {
    __shared__ int cnt[NPB];
    __shared__ int cur[NPB];
    int b = blockIdx.x;
    int beg = bbase[b], end = bbase[b + 1];
    if (threadIdx.x < NPB) cnt[threadIdx.x] = 0;
    __syncthreads();
    for (int i = beg + threadIdx.x; i < end; i += 256)
        atomicAdd(&cnt[eb[i] & 63], 1);
    __syncthreads();
    if (threadIdx.x < NPB) {  // wave 0: 64-lane inclusive shfl scan
        int v = cnt[threadIdx.x];
        int s = v;
#pragma unroll
        for (int o = 1; o < NPB; o <<= 1) {
            int u = __shfl_up(s, o, 64);
            if (threadIdx.x >= (unsigned)o) s += u;
        }
        int e0 = beg + s - v;
        cur[threadIdx.x] = e0;
        int node = b * NPB + threadIdx.x;
        if (node < n) {
            offs[node] = e0;
            dinv[node] = rsqrtf((float)v + 1.0f);  // +1 self loop
        }
    }
    __syncthreads();
    for (int i = beg + threadIdx.x; i < end; i += 256) {
        unsigned p = eb[i];
        int pos = atomicAdd(&cur[p & 63], 1);
        ss[pos] = (int)(p >> 6);
    }
}

// --- weight prep: W1t[c][k]=fp16(W1[k][c]); W2t 64x128, rows>=40 zero ---
__global__ __launch_bounds__(256) void k_prep(const float* __restrict__ W1,
        const float* __restrict__ W2, _Float16* __restrict__ W1t,
        _Float16* __restrict__ W2t) {
    int i = blockIdx.x * 256 + threadIdx.x;
    if (i < 128 * 128) {
        int c = i >> 7, k = i & 127;
        W1t[c * 128 + k] = (_Float16)W1[k * 128 + c];
    }
    int j = i - 128 * 128;
    if (j >= 0 && j < 64 * 128) {
        int c = j >> 7, k = j & 127;
        W2t[c * 128 + k] = (c < CDIM) ? (_Float16)W2[k * CDIM + c] : (_Float16)0.f;
    }
}

// Hp[r][c] = fp16( (X[r] @ W1)[c] * dinv[r] )  -- MFMA 16x16x32 f16
__global__ __launch_bounds__(256) void k_gemm1(const float* __restrict__ X,
        const _Float16* __restrict__ W1t, const float* __restrict__ dinv,
        _Float16* __restrict__ Hp, int n) {
    __shared__ _Float16 xh[64][136];   // +8 pad: 2-way LDS conflict (free)
    __shared__ _Float16 wt[128][136];
    int t = threadIdx.x;
    int r0 = blockIdx.x * 64;
    for (int i = t; i < 64 * 32; i += 256) {
        int r = i >> 5, c4 = (i & 31) * 4;
        int gr = r0 + r;
        float4 v = make_float4(0.f, 0.f, 0.f, 0.f);
        if (gr < n) v = *(const float4*)&X[(size_t)gr * 128 + c4];
        h4 hv; hv[0] = (_Float16)v.x; hv[1] = (_Float16)v.y;
               hv[2] = (_Float16)v.z; hv[3] = (_Float16)v.w;
        *(h4*)&xh[r][c4] = hv;
    }
    for (int i = t; i < 128 * 16; i += 256) {
        int r = i >> 4, c8 = (i & 15) * 8;
        *(uint4*)&wt[r][c8] = *(const uint4*)&W1t[r * 128 + c8];
    }
    __syncthreads();
    int wid = t >> 6, lane = t & 63;
    int fr = lane & 15, fg = lane >> 4;
    f4 acc[8];
#pragma unroll
    for (int ct = 0; ct < 8; ++ct) acc[ct] = (f4){0.f, 0.f, 0.f, 0.f};
#pragma unroll
    for (int ks = 0; ks < 4; ++ks) {
        h8 a = *(const h8*)&xh[wid * 16 + fr][ks * 32 + fg * 8];
#pragma unroll
        for (int ct = 0; ct < 8; ++ct) {
            h8 b = *(const h8*)&wt[ct * 16 + fr][ks * 32 + fg * 8];
            acc[ct] = __builtin_amdgcn_mfma_f32_16x16x32_f16(a, b, acc[ct], 0, 0, 0);
        }
    }
    int rbase = r0 + wid * 16 + fg * 4;  // C/D: row=(lane>>4)*4+reg, col=lane&15
    float dv[4];
#pragma unroll
    for (int rg = 0; rg < 4; ++rg) dv[rg] = (rbase + rg < n) ? dinv[rbase + rg] : 0.f;
#pragma unroll
    for (int ct = 0; ct < 8; ++ct)
#pragma unroll
        for (int rg = 0; rg < 4; ++rg) {
            int gr = rbase + rg;
            if (gr < n) Hp[(size_t)gr * 128 + ct * 16 + fr] = (_Float16)(acc[ct][rg] * dv[rg]);
        }
}

// h1[d] = fp16(relu(dinv[d]*(hp[d]+sum hp[s]) + b1))
// 16B/lane: 4 neighbor rows per load instruction; shfl_xor(16,32) fold.
__global__ __launch_bounds__(256) void k_agg128(const int* __restrict__ ss,
        const int* __restrict__ offs, const _Float16* __restrict__ hp,
        const float* __restrict__ b1, const float* __restrict__ dinv,
        _Float16* __restrict__ h1, int n, int E) {
    int w = (blockIdx.x * 256 + threadIdx.x) >> 6;
    int lane = threadIdx.x & 63;
    if (w >= n) return;
    int beg = offs[w];
    int end = (w == n - 1) ? E : offs[w + 1];
    const h8* hpv = (const h8*)hp;
    int g = lane >> 4, c = lane & 15;
    h8 sv = hpv[(size_t)w * 16 + c];  // self row (broadcast across groups)
    float acc[8];
#pragma unroll
    for (int i = 0; i < 8; ++i) acc[i] = (g == 0) ? (float)sv[i] : 0.f;
    int j = beg;
    for (; j + 7 < end; j += 8) {  // 8 edges per iter, 2 loads in flight
        int s0 = ss[j + g];
        int s1 = ss[j + 4 + g];
        h8 v0 = hpv[(size_t)s0 * 16 + c];
        h8 v1 = hpv[(size_t)s1 * 16 + c];
#pragma unroll
        for (int i = 0; i < 8; ++i) acc[i] += (float)v0[i] + (float)v1[i];
    }
    for (; j < end; j += 4) {
        int idx = j + g;
        if (idx < end) {
            int s = ss[idx];
            h8 v = hpv[(size_t)s * 16 + c];
#pragma unroll
            for (int i = 0; i < 8; ++i) acc[i] += (float)v[i];
        }
    }
#pragma unroll
    for (int i = 0; i < 8; ++i) {  // fold 4 group-partials
        acc[i] += __shfl_xor(acc[i], 16);
        acc[i] += __shfl_xor(acc[i], 32);
    }
    if (lane < 16) {  // lane l holds cols 8l..8l+7
        float dvv = dinv[w];
        const float4 bb0 = *(const float4*)&b1[8 * lane];
        const float4 bb1 = *(const float4*)&b1[8 * lane + 4];
        h8 o;
        o[0] = (_Float16)fmaxf(fmaf(dvv, acc[0], bb0.x), 0.f);
        o[1] = (_Float16)fmaxf(fmaf(dvv, acc[1], bb0.y), 0.f);
        o[2] = (_Float16)fmaxf(fmaf(dvv, acc[2], bb0.z), 0.f);
        o[3] = (_Float16)fmaxf(fmaf(dvv, acc[3], bb0.w), 0.f);
        o[4] = (_Float16)fmaxf(fmaf(dvv, acc[4], bb1.x), 0.f);
        o[5] = (_Float16)fmaxf(fmaf(dvv, acc[5], bb1.y), 0.f);
        o[6] = (_Float16)fmaxf(fmaf(dvv, acc[6], bb1.z), 0.f);
        o[7] = (_Float16)fmaxf(fmaf(dvv, acc[7], bb1.w), 0.f);
        *(h8*)&h1[(size_t)w * 128 + 8 * lane] = o;
    }
}

// Hp2[r][c] = fp16( (h1[r] @ W2)[c] * dinv[r] ), 64-col padded (cols>=40 = 0)
__global__ __launch_bounds__(256) void k_gemm2(const _Float16* __restrict__ H1,
        const _Float16* __restrict__ W2t, const float* __restrict__ dinv,
        _Float16* __restrict__ Hp2, int n) {
    __shared__ _Float16 xh[64][136];
    __shared__ _Float16 wt[64][136];
    int t = threadIdx.x;
    int r0 = blockIdx.x * 64;
    for (int i = t; i < 64 * 16; i += 256) {
        int r = i >> 4, c8 = (i & 15) * 8;
        int gr = r0 + r;
        uint4 v = make_uint4(0u, 0u, 0u, 0u);
        if (gr < n) v = *(const uint4*)&H1[(size_t)gr * 128 + c8];
        *(uint4*)&xh[r][c8] = v;
    }
    for (int i = t; i < 64 * 16; i += 256) {
        int r = i >> 4, c8 = (i & 15) * 8;
        *(uint4*)&wt[r][c8] = *(const uint4*)&W2t[r * 128 + c8];
    }
    __syncthreads();
    int wid = t >> 6, lane = t & 63;
    int fr = lane & 15, fg = lane >> 4;
    f4 acc[4];
#pragma unroll
    for (int ct = 0; ct < 4; ++ct) acc[ct] = (f4){0.f, 0.f, 0.f, 0.f};
#pragma unroll
    for (int ks = 0; ks < 4; ++ks) {
        h8 a = *(const h8*)&xh[wid * 16 + fr][ks * 32 + fg * 8];
#pragma unroll
        for (int ct = 0; ct < 4; ++ct) {
            h8 b = *(const h8*)&wt[ct * 16 + fr][ks * 32 + fg * 8];
            acc[ct] = __builtin_amdgcn_mfma_f32_16x16x32_f16(a, b, acc[ct], 0, 0, 0);
        }
    }
    int rbase = r0 + wid * 16 + fg * 4;
    float dv[4];
#pragma unroll
    for (int rg = 0; rg < 4; ++rg) dv[rg] = (rbase + rg < n) ? dinv[rbase + rg] : 0.f;
#pragma unroll
    for (int ct = 0; ct < 4; ++ct)
#pragma unroll
        for (int rg = 0; rg < 4; ++rg) {
            int gr = rbase + rg;
            if (gr < n) Hp2[(size_t)gr * 64 + ct * 16 + fr] = (_Float16)(acc[ct][rg] * dv[rg]);
        }
}

// h2[d] = relu(dinv[d]*(hp2[d]+sum hp2[s]) + b2) -> d_out (40 fp32/row)
// hp2 rows are 64 fp16 (128B); 16B/lane -> 8 rows per load instruction.
__global__ __launch_bounds__(256) void k_agg40(const int* __restrict__ ss,
        const int* __restrict__ offs, const _Float16* __restrict__ hp,
        const float* __restrict__ b2, const float* __restrict__ dinv,
        float* __restrict__ h2out, int n, int E) {
    int w = (blockIdx.x * 256 + threadIdx.x) >> 6;
    int lane = threadIdx.x & 63;
    if (w >= n) return;
    int beg = offs[w];
    int end = (w == n - 1) ? E : offs[w + 1];
    const h8* hpv = (const h8*)hp;
    int g = lane >> 3, c = lane & 7;
    h8 sv = hpv[(size_t)w * 8 + c];  // self row
    float acc[8];
#pragma unroll
    for (int i = 0; i < 8; ++i) acc[i] = (g == 0) ? (float)sv[i] : 0.f;
    int j = beg;
    for (; j + 15 < end; j += 16) {  // 16 edges per iter, 2 loads in flight
        int s0 = ss[j + g];
        int s1 = ss[j + 8 + g];
        h8 v0 = hpv[(size_t)s0 * 8 + c];
        h8 v1 = hpv[(size_t)s1 * 8 + c];
#pragma unroll
        for (int i = 0; i < 8; ++i) acc[i] += (float)v0[i] + (float)v1[i];
    }
    for (; j < end; j += 8) {
        int idx = j + g;
        if (idx < end) {
            int s = ss[idx];
            h8 v = hpv[(size_t)s * 8 + c];
#pragma unroll
            for (int i = 0; i < 8; ++i) acc[i] += (float)v[i];
        }
    }
#pragma unroll
    for (int i = 0; i < 8; ++i) {  // fold 8 group-partials
        acc[i] += __shfl_xor(acc[i], 8);
        acc[i] += __shfl_xor(acc[i], 16);
        acc[i] += __shfl_xor(acc[i], 32);
    }
    if (lane < 5) {  // lane l holds cols 8l..8l+7; cols 40..63 are padding
        float dvv = dinv[w];
        const float4 bb0 = *(const float4*)&b2[8 * lane];
        const float4 bb1 = *(const float4*)&b2[8 * lane + 4];
        float4 r0, r1;
        r0.x = fmaxf(fmaf(dvv, acc[0], bb0.x), 0.f);
        r0.y = fmaxf(fmaf(dvv, acc[1], bb0.y), 0.f);
        r0.z = fmaxf(fmaf(dvv, acc[2], bb0.z), 0.f);
        r0.w = fmaxf(fmaf(dvv, acc[3], bb0.w), 0.f);
        r1.x = fmaxf(fmaf(dvv, acc[4], bb1.x), 0.f);
        r1.y = fmaxf(fmaf(dvv, acc[5], bb1.y), 0.f);
        r1.z = fmaxf(fmaf(dvv, acc[6], bb1.z), 0.f);
        r1.w = fmaxf(fmaf(dvv, acc[7], bb1.w), 0.f);
        *(float4*)&h2out[(size_t)w * CDIM + 8 * lane] = r0;
        *(float4*)&h2out[(size_t)w * CDIM + 8 * lane + 4] = r1;
    }
}

// lin_out = h2 @ Wlin + blin  (h2 read back from d_out)
__global__ __launch_bounds__(256) void k_final(const float* __restrict__ h2,
        const float* __restrict__ Wlin, const float* __restrict__ blin,
        float* __restrict__ lin_out, int n) {
    __shared__ float wl[CDIM * CDIM];
    __shared__ float hs[32 * CDIM];
    int t = threadIdx.x;
    int r0 = blockIdx.x * 32;
    for (int i = t; i < CDIM * CDIM; i += 256) wl[i] = Wlin[i];
    int lim = n * CDIM - r0 * CDIM;
    for (int i = t; i < 32 * CDIM; i += 256)
        hs[i] = (i < lim) ? h2[(size_t)r0 * CDIM + i] : 0.f;
    __syncthreads();
    for (int i = t; i < 32 * CDIM; i += 256) {
        int r = i / CDIM, c = i % CDIM;
        int gr = r0 + r;
        if (gr >= n) continue;
        float acc = blin[c];
#pragma unroll
        for (int k = 0; k < CDIM; ++k) acc = fmaf(hs[r * CDIM + k], wl[k * CDIM + c], acc);
        lin_out[(size_t)gr * CDIM + c] = acc;
    }
}

extern "C" void kernel_launch(void* const* d_in, const int* in_sizes, int n_in,
                              void* d_out, int out_size, void* d_ws, size_t ws_size,
                              hipStream_t stream) {
    const float* x    = (const float*)d_in[0];
    const int*   ei   = (const int*)d_in[1];
    const float* W1   = (const float*)d_in[2];
    const float* b1   = (const float*)d_in[3];
    const float* W2   = (const float*)d_in[4];
    const float* b2   = (const float*)d_in[5];
    const float* Wlin = (const float*)d_in[6];
    const float* blin = (const float*)d_in[7];
    float* out = (float*)d_out;

    const int n = in_sizes[0] / FDIM;
    const int E = in_sizes[1] / 2;
    const int* src = ei;
    const int* dst = ei + E;
    const int nb = (n + NPB - 1) / NPB;

    char* ws = (char*)d_ws;
    size_t off = 0;
    int*       bcnt  = (int*)(ws + off);       off = AL512(off + (size_t)nb * 4);
    int*       bbase = (int*)(ws + off);       off = AL512(off + (size_t)(nb + 1) * 4);
    int*       bcur  = (int*)(ws + off);       off = AL512(off + (size_t)nb * 4);
    unsigned*  eb    = (unsigned*)(ws + off);  off = AL512(off + (size_t)E * 4);
    int*       offs  = (int*)(ws + off);       off = AL512(off + (size_t)n * 4);
    int*       ss    = (int*)(ws + off);       off = AL512(off + (size_t)E * 4);
    float*     dinv  = (float*)(ws + off);     off = AL512(off + (size_t)n * 4);
    _Float16*  W1t   = (_Float16*)(ws + off);  off = AL512(off + (size_t)128 * 128 * 2);
    _Float16*  W2t   = (_Float16*)(ws + off);  off = AL512(off + (size_t)64 * 128 * 2);
    _Float16*  hp1   = (_Float16*)(ws + off);  off = AL512(off + (size_t)n * FDIM * 2);
    _Float16*  h1h   = (_Float16*)(ws + off);  off = AL512(off + (size_t)n * FDIM * 2);
    _Float16*  hp2   = (_Float16*)(ws + off);  off = AL512(off + (size_t)n * 64 * 2);
    (void)ws_size; (void)n_in; (void)out_size;

    float* h2_out  = out;
    float* lin_out = out + (size_t)n * CDIM;

    // weight prep (independent) + CSR build
    k_prep<<<(128 * 128 + 64 * 128 + 255) / 256, 256, 0, stream>>>(W1, W2, W1t, W2t);
    hipMemsetAsync(bcnt, 0, (size_t)nb * 4, stream);
    k_bhist<<<256, 256, 0, stream>>>(dst, bcnt, E, nb);
    k_bscan<<<1, 1024, 0, stream>>>(bcnt, bbase, bcur, nb, E);
    k_partition<<<(E + CH - 1) / CH, 256, 0, stream>>>(src, dst, bcur, eb, E, nb);
    k_bucket_csr<<<nb, 256, 0, stream>>>(eb, bbase, offs, dinv, ss, n);

    // conv1
    k_gemm1<<<(n + 63) / 64, 256, 0, stream>>>(x, W1t, dinv, hp1, n);
    k_agg128<<<(n * 64 + 255) / 256, 256, 0, stream>>>(ss, offs, hp1, b1, dinv, h1h, n, E);

    // conv2
    k_gemm2<<<(n + 63) / 64, 256, 0, stream>>>(h1h, W2t, dinv, hp2, n);
    k_agg40<<<(n * 64 + 255) / 256, 256, 0, stream>>>(ss, offs, hp2, b2, dinv, h2_out, n, E);

    // linear head
    k_final<<<(n + 31) / 32, 256, 0, stream>>>(h2_out, Wlin, blin, lin_out, n);
}